// Round 1
// 115.982 us; speedup vs baseline: 1.0389x; 1.0389x over previous
//
#include <hip/hip_runtime.h>
#include <math.h>

// DetectionLoss: gather-based exact reimplementation, wave-per-(batch,scale).
// pred_p3 (64,11,160,160) f32, pred_p4 (64,11,80,80), pred_p5 (64,11,40,40),
// targets_cls (64,60) i32, targets_box (64,60,4) f32.
// Only B*T=3840 cells/scale are positive -> pure gather problem.
// Collision tie-break: LAST target index wins the box (matches serial scatter
// lowering, verified absmax 0.0 in prior rounds); class target is the union.
//
// Structure: 192 blocks = (scale s, batch b), 64 threads = ONE WAVE.
//  - no LDS, no __syncthreads in the main kernel: target keys/classes are
//    exchanged with __shfl, partial sums reduced with a __shfl_xor butterfly.
//  - 3x the memory-level parallelism of the previous 64-block version for the
//    scattered winner-gather (10 cache lines per winner, L3-cold every
//    iteration because the harness's 275 MB poison fill evicts the inputs).

#define NCLS 6
#define NT   60
#define NB   64
#define NS   3

__device__ __forceinline__ float iou_fn(float x1, float y1, float w1, float h1,
                                        float x2, float y2, float w2, float h2) {
    // mirror reference arithmetic exactly (compute xyxy, subtract back)
    float x11 = x1 - w1 * 0.5f, y11 = y1 - h1 * 0.5f;
    float x12 = x1 + w1 * 0.5f, y12 = y1 + h1 * 0.5f;
    float x21 = x2 - w2 * 0.5f, y21 = y2 - h2 * 0.5f;
    float x22 = x2 + w2 * 0.5f, y22 = y2 + h2 * 0.5f;
    float iw = fmaxf(fminf(x12, x22) - fmaxf(x11, x21), 0.0f);
    float ih = fmaxf(fminf(y12, y22) - fmaxf(y11, y21), 0.0f);
    float inter = iw * ih;
    float a1 = (x12 - x11) * (y12 - y11);
    float a2 = (x22 - x21) * (y22 - y21);
    return inter / (a1 + a2 - inter + 1e-7f);
}

// grid = NS*NB = 192 blocks, block = 64 (one wave, no barriers anywhere)
__global__ __launch_bounds__(64)
void detloss_main(const float* __restrict__ p3, const float* __restrict__ p4,
                  const float* __restrict__ p5, const int* __restrict__ tcls,
                  const float* __restrict__ tbox, float* __restrict__ part) {
    const int bs = blockIdx.x;      // 0..191
    const int s  = bs >> 6;         // scale 0..2
    const int b  = bs & 63;         // batch
    const int t  = threadIdx.x;     // lane 0..63; lanes >= NT are padding
    const bool valid = (t < NT);

    float tx = 0.f, ty = 0.f, tw = 0.f, th = 0.f;
    int   cls = 0;
    int   key = -1 - t;             // distinct negatives: never match a real key
    if (valid) {
        const float4 tb = *reinterpret_cast<const float4*>(tbox + (size_t)(b * NT + t) * 4);
        tx = tb.x; ty = tb.y; tw = tb.z; th = tb.w;
        cls = tcls[b * NT + t];
        const int W = 160 >> s;     // H == W at every scale
        int gx = (int)(tx * (float)W);  // f32 mul then trunc, same as jnp
        int gy = (int)(ty * (float)W);
        gx = min(max(gx, 0), W - 1);
        gy = min(max(gy, 0), W - 1);
        key = (gy << 8) | gx;       // W<=160<256 -> unique encoding
    }

    // All-to-all within the wave: build class union + last-index-wins flag.
    int  mask   = 0;
    bool winner = valid;
    for (int t2 = 0; t2 < NT; ++t2) {
        const int k2 = __shfl(key, t2);
        const int c2 = __shfl(cls, t2);
        if (k2 == key) {
            mask |= 1 << c2;
            if (t2 > t) winner = false;   // last index wins the cell
        }
    }

    float n_pos = 0.f, bce_s = 0.f, iou_s = 0.f, inn_s = 0.f;
    if (winner) {
        const int W  = 160 >> s;
        const int HW = W * W;
        const float* pred = (s == 0) ? p3 : ((s == 1) ? p4 : p5);
        const int gx = key & 255, gy = key >> 8;
        const float* cell = pred + (size_t)b * 11 * HW + (size_t)gy * W + gx;

        // BCE over the 6 class channels at this cell
        float bce = 0.0f;
        #pragma unroll
        for (int c = 0; c < NCLS; ++c) {
            float xv = cell[(size_t)c * HW];
            float tv = (float)((mask >> c) & 1);
            bce += fmaxf(xv, 0.0f) - xv * tv + log1pf(expf(-fabsf(xv)));
        }
        // box channels are 7..10 (channel 6 skipped by NC+1:)
        float px = cell[(size_t)7 * HW], py = cell[(size_t)8 * HW];
        float pw = cell[(size_t)9 * HW], ph = cell[(size_t)10 * HW];

        n_pos = 1.0f;
        bce_s = bce;
        iou_s = 1.0f - iou_fn(px, py, pw, ph, tx, ty, tw, th);
        inn_s = 1.0f - iou_fn(px, py, pw * 0.7f, ph * 0.7f,
                              tx, ty, tw * 0.7f, th * 0.7f);
    }

    // 64-lane butterfly reduction (non-winners/padding contribute 0)
    #pragma unroll
    for (int off = 32; off > 0; off >>= 1) {
        n_pos += __shfl_xor(n_pos, off);
        bce_s += __shfl_xor(bce_s, off);
        iou_s += __shfl_xor(iou_s, off);
        inn_s += __shfl_xor(inn_s, off);
    }

    if (t == 0) {
        float4 o = make_float4(n_pos, bce_s, iou_s, inn_s);
        *reinterpret_cast<float4*>(part + (size_t)bs * 4) = o;  // every slot written: poison-safe
    }
}

// 1 block x 256 threads: lane-coalesced float4 load of all 192 partials,
// wave w (=scale for w<3) butterfly-reduces its 64 batches.
__global__ __launch_bounds__(256)
void detloss_final(const float* __restrict__ part, float* __restrict__ out) {
    __shared__ float acc[NS][4];
    const int tid = threadIdx.x;

    float4 v = make_float4(0.f, 0.f, 0.f, 0.f);
    if (tid < NS * NB) v = *reinterpret_cast<const float4*>(part + (size_t)tid * 4);

    float n = v.x, c = v.y, io = v.z, in_ = v.w;
    #pragma unroll
    for (int off = 32; off > 0; off >>= 1) {
        n   += __shfl_xor(n, off);
        c   += __shfl_xor(c, off);
        io  += __shfl_xor(io, off);
        in_ += __shfl_xor(in_, off);
    }
    if (tid < NS * NB && (tid & 63) == 0) {
        const int s = tid >> 6;
        acc[s][0] = n; acc[s][1] = c; acc[s][2] = io; acc[s][3] = in_;
    }
    __syncthreads();

    if (tid == 0) {
        float cls_total = 0.0f, box_total = 0.0f;
        #pragma unroll
        for (int s = 0; s < NS; ++s) {
            float denom      = acc[s][0] + 1e-8f;
            float cls_loss   = acc[s][1] / denom;
            float iou_term   = acc[s][2] / denom;
            float inner_term = acc[s][3] / denom;
            float inner_iou  = 0.5f * iou_term + 0.5f * inner_term;  // (1-INNER_W), INNER_W
            float box_loss   = 0.5f * iou_term + 0.5f * inner_iou;
            cls_total += cls_loss;
            box_total += box_loss;
        }
        cls_total *= (1.0f / 3.0f);
        box_total *= (1.0f / 3.0f);
        out[0] = 0.5f * cls_total + 7.5f * box_total;  // CLS_W, BOX_W
        out[1] = cls_total;
        out[2] = box_total;
    }
}

extern "C" void kernel_launch(void* const* d_in, const int* in_sizes, int n_in,
                              void* d_out, int out_size, void* d_ws, size_t ws_size,
                              hipStream_t stream) {
    const float* p3   = (const float*)d_in[0];
    const float* p4   = (const float*)d_in[1];
    const float* p5   = (const float*)d_in[2];
    const int*   tcls = (const int*)d_in[3];
    const float* tbox = (const float*)d_in[4];
    float* out  = (float*)d_out;
    float* part = (float*)d_ws;  // NS*NB*4 floats = 3 KB

    detloss_main<<<NS * NB, 64, 0, stream>>>(p3, p4, p5, tcls, tbox, part);
    detloss_final<<<1, 256, 0, stream>>>(part, out);
}